// Round 2
// baseline (3289.355 us; speedup 1.0000x reference)
//
#include <hip/hip_runtime.h>
#include <hip/hip_bf16.h>

// MolGAN discriminator: 3x RGCN(+BN over atom axis+LeakyReLU) + masked-sum readout.
// Per layer: Z[b,m] = [act(h) | adj_0@act(h) | ... | adj_3@act(h)]  (K = 5*din)
// then hpre = Z @ [ws; wr0..wr3] + bias  -> ONE standard GEMM per layer.
// BN(atom axis, 9 channels): stats accumulated in-GEMM (fp32, exact), finalized by tiny
// kernel; affine+leaky applied on NEXT layer's load (k_pre / readout epilogue).
// Workspace-adaptive: Path A (>=250MB ws) stores h2; Path B recomputes layer-2 GEMM
// twice (stats pass + fused-readout pass), needs only ~137MB.

#define NB 32768
#define NA 9
#define NR 4
#define D0 5
#define D1 64
#define D2 128
#define D3 256
#define EPS 1e-5f
#define SLOPE 0.2f
#define NSLOT 64

#define CHB1 4096    // layer-1 chunk (8 chunks)  : Z1 = 4096*9*320*2 = 23,592,960 B
#define CHB2 2048    // layer-2 chunk (16 chunks) : Z2 = 2048*9*640*2 = 23,592,960 B

typedef __hip_bfloat16 bf16;

__device__ __forceinline__ float bf2f(bf16 v) { return __bfloat162float(v); }
__device__ __forceinline__ bf16  f2bf(float v) { return __float2bfloat16(v); }

// ---------------- zero init: stats slots + fins + out ----------------
__global__ __launch_bounds__(256) void k_zero(float* __restrict__ hdr, float* __restrict__ out)
{
    int idx = blockIdx.x * 256 + threadIdx.x;
    if (idx < NB) out[idx] = 0.f;
    if (idx < 6240) hdr[idx] = 0.f;   // 3*64*32 slots + 3*32 fins (contiguous)
}

// ---------------- layer 0 (din=5, no BN before it) ----------------
__global__ __launch_bounds__(256) void k_layer0(
    const float* __restrict__ feats,   // [B,9,5]
    const float* __restrict__ adj,     // [B,4,9,9]
    const float* __restrict__ ws,      // [5,64]
    const float* __restrict__ wr,      // [4,5,64]
    const float* __restrict__ bias,    // [64]
    bf16* __restrict__ hpre,           // [B,9,64]
    float* __restrict__ slots)
{
    __shared__ float Wsh[5][5][64];    // [s][k][e], s=0 self
    __shared__ float Bsh[64];
    __shared__ float Adj[4][4][9][9];  // [b_l][r][m][n]
    __shared__ float Hsh[4][9][5];
    __shared__ float bstat[18];

    int tid = threadIdx.x;
    int bl  = tid >> 6;                // 0..3 (one wave per molecule)
    int e   = tid & 63;
    int b0  = blockIdx.x * 4;

    for (int i = tid; i < 5*64; i += 256) Wsh[0][i/64][i%64] = ws[i];
    for (int i = tid; i < 4*5*64; i += 256) {
        int s = i / 320, rem = i % 320;
        Wsh[1+s][rem/64][rem%64] = wr[i];
    }
    if (tid < 64) Bsh[tid] = bias[tid];
    if (tid < 18) bstat[tid] = 0.f;
    {
        const float* ap = adj + (size_t)(b0 + bl) * (NR*NA*NA);
        float* dst = &Adj[bl][0][0][0];
        for (int i = e; i < NR*NA*NA; i += 64) dst[i] = ap[i];
    }
    {
        const float* fp = feats + (size_t)(b0 + bl) * (NA*D0);
        float* dst = &Hsh[bl][0][0];
        for (int i = e; i < NA*D0; i += 64) dst[i] = fp[i];
    }
    __syncthreads();

    float X[5][9];
    #pragma unroll
    for (int s = 0; s < 5; s++)
        #pragma unroll
        for (int n = 0; n < 9; n++) {
            float a = 0.f;
            #pragma unroll
            for (int k = 0; k < 5; k++) a += Hsh[bl][n][k] * Wsh[s][k][e];
            X[s][n] = a;
        }
    float bv = Bsh[e];
    float out[9];
    #pragma unroll
    for (int m = 0; m < 9; m++) {
        float a = X[0][m] + bv;
        #pragma unroll
        for (int r = 0; r < 4; r++)
            #pragma unroll
            for (int n = 0; n < 9; n++)
                a += Adj[bl][r][m][n] * X[1+r][n];
        out[m] = a;
    }
    bf16* hp = hpre + (size_t)(b0 + bl) * (NA*D1) + e;
    #pragma unroll
    for (int m = 0; m < 9; m++) hp[m*D1] = f2bf(out[m]);

    #pragma unroll
    for (int m = 0; m < 9; m++) {
        float s = out[m], q = out[m]*out[m];
        #pragma unroll
        for (int off = 32; off > 0; off >>= 1) {
            s += __shfl_xor(s, off, 64);
            q += __shfl_xor(q, off, 64);
        }
        if (e == 0) { atomicAdd(&bstat[m], s); atomicAdd(&bstat[9+m], q); }
    }
    __syncthreads();
    if (tid < 9) {
        float* sl = slots + (size_t)(blockIdx.x & (NSLOT-1)) * 32;
        atomicAdd(&sl[tid],      bstat[tid]);
        atomicAdd(&sl[16+tid],   bstat[9+tid]);
    }
}

// ---------------- BN finalize ----------------
template<int DOUT>
__global__ void k_finalize(const float* __restrict__ slots,
                           const float* __restrict__ g, const float* __restrict__ be,
                           float* __restrict__ fin)   // [32]: scale@0..8, shift@16..24
{
    int n = threadIdx.x;
    if (n < 9) {
        float s = 0.f, q = 0.f;
        for (int i = 0; i < NSLOT; i++) { s += slots[i*32+n]; q += slots[i*32+16+n]; }
        float cnt = (float)NB * (float)DOUT;
        float mean = s / cnt;
        float var  = q / cnt - mean*mean;
        float sc   = g[n] * rsqrtf(var + EPS);
        fin[n]    = sc;
        fin[16+n] = be[n] - mean * sc;
    }
}

// ---------------- pre-kernel: act(prev) and Z = [h | adj_r @ h] ----------------
template<int DIN>
__global__ __launch_bounds__(256) void k_pre(
    const bf16* __restrict__ hprev,    // [B,9,DIN] full
    const float* __restrict__ fin,
    const float* __restrict__ adj,     // [B,4,9,9] full
    bf16* __restrict__ Z,              // [CHB*9, 5*DIN] chunk-local
    int bbase)
{
    constexpr int KPT = DIN / 64;
    __shared__ float Adj[4][4][9][9];
    int tid = threadIdx.x;
    int bl = tid >> 6, lane = tid & 63;
    int b  = bbase + blockIdx.x * 4 + bl;
    {
        const float* ap = adj + (size_t)b * (NR*NA*NA);
        float* dst = &Adj[bl][0][0][0];
        for (int i = lane; i < NR*NA*NA; i += 64) dst[i] = ap[i];
    }
    float sc[9], sh[9];
    #pragma unroll
    for (int n = 0; n < 9; n++) { sc[n] = fin[n]; sh[n] = fin[16+n]; }
    __syncthreads();

    int brel = blockIdx.x * 4 + bl;
    const bf16* hp = hprev + (size_t)b * (NA*DIN);
    bf16* zp = Z + (size_t)brel * (NA*5*DIN);

    #pragma unroll
    for (int kk = 0; kk < KPT; kk++) {
        int k = lane + kk*64;
        float h[9];
        #pragma unroll
        for (int n = 0; n < 9; n++) {
            float v = bf2f(hp[n*DIN + k]);
            v = sc[n]*v + sh[n];
            h[n] = v > 0.f ? v : SLOPE*v;
        }
        #pragma unroll
        for (int m = 0; m < 9; m++) zp[(size_t)m*(5*DIN) + k] = f2bf(h[m]);
        #pragma unroll
        for (int r = 0; r < 4; r++) {
            #pragma unroll
            for (int m = 0; m < 9; m++) {
                float a = 0.f;
                #pragma unroll
                for (int n = 0; n < 9; n++) a += Adj[bl][r][m][n] * h[n];
                zp[(size_t)m*(5*DIN) + (1+r)*DIN + k] = f2bf(a);
            }
        }
    }
}

// ---------------- main GEMM ----------------
// MODE 0: store hout bf16 + BN stats.  MODE 1: BN stats only.
// MODE 2: fused epilogue BN+leaky+mask+fc dot -> atomicAdd out[b].
template<int DIN, int DOUT, int MODE>
__global__ __launch_bounds__(256) void k_gemm(
    const bf16* __restrict__ Z,        // [CHB*9, 5*DIN]
    const float* __restrict__ ws,      // [DIN, DOUT]
    const float* __restrict__ wr,      // [4, DIN, DOUT]
    const float* __restrict__ bias,    // [DOUT]
    bf16* __restrict__ hout,           // [B,9,DOUT] (MODE 0)
    float* __restrict__ slots,         // (MODE 0/1)
    int bbase,
    const float* __restrict__ fin,     // (MODE 2)
    const float* __restrict__ mask,    // (MODE 2)
    const float* __restrict__ fcw,     // (MODE 2)
    float* __restrict__ outp)          // (MODE 2)
{
    constexpr int K5  = 5*DIN;
    constexpr int NPT = DOUT / 32;
    __shared__ float As[16][64];       // [k][row]
    __shared__ float Wt[16][DOUT];     // [k][n]
    __shared__ float rowsum[64][2];
    __shared__ float bstat[18];
    __shared__ float sfin[32];

    int tid = threadIdx.x;
    int tx = tid & 31, ty = tid >> 5;
    int mrow0 = blockIdx.x * 64;       // chunk-local row base

    if (tid < 18) bstat[tid] = 0.f;
    if constexpr (MODE == 2) { if (tid < 32) sfin[tid] = fin[tid]; }

    float acc[8][NPT];
    #pragma unroll
    for (int i = 0; i < 8; i++)
        #pragma unroll
        for (int j = 0; j < NPT; j++) acc[i][j] = 0.f;

    for (int kc = 0; kc < K5/16; kc++) {
        int kg = kc*16;
        int s = kg / DIN, k0 = kg % DIN;
        const float* wp = (s == 0) ? (ws + (size_t)k0*DOUT)
                                   : (wr + ((size_t)(s-1)*DIN + k0)*DOUT);
        for (int i = tid*4; i < 16*DOUT; i += 1024) {
            float4 v = *(const float4*)(wp + i);
            ((float4*)(&Wt[0][0]))[i >> 2] = v;
        }
        {
            int rl = tid >> 2;         // 0..63
            int q  = tid & 3;
            const bf16* zr = Z + (size_t)(mrow0 + rl) * K5 + kg + q*4;
            bf16 az[4] __attribute__((aligned(8)));
            *(uint2*)az = *(const uint2*)zr;
            #pragma unroll
            for (int j = 0; j < 4; j++) As[q*4+j][rl] = bf2f(az[j]);
        }
        __syncthreads();
        #pragma unroll
        for (int k = 0; k < 16; k++) {
            float a[8], w[NPT];
            #pragma unroll
            for (int i = 0; i < 8; i++) a[i] = As[k][ty*8 + i];
            #pragma unroll
            for (int j = 0; j < NPT; j++) w[j] = Wt[k][tx*NPT + j];
            #pragma unroll
            for (int i = 0; i < 8; i++)
                #pragma unroll
                for (int j = 0; j < NPT; j++) acc[i][j] += a[i]*w[j];
        }
        __syncthreads();
    }

    float bsv[NPT];
    #pragma unroll
    for (int j = 0; j < NPT; j++) bsv[j] = bias[tx*NPT + j];

    if constexpr (MODE == 2) {
        // fused BN + leaky + mask + fc-dot readout
        float wv[NPT];
        #pragma unroll
        for (int j = 0; j < NPT; j++) wv[j] = fcw[tx*NPT + j];
        #pragma unroll
        for (int i = 0; i < 8; i++) {
            int grow = bbase*NA + mrow0 + ty*8 + i;
            int b = grow / 9, n = grow % 9;
            float scv = sfin[n], shv = sfin[16+n];
            float part = 0.f;
            #pragma unroll
            for (int j = 0; j < NPT; j++) {
                float v = acc[i][j] + bsv[j];
                float y = scv*v + shv;
                y = y > 0.f ? y : SLOPE*y;
                part += y * wv[j];
            }
            #pragma unroll
            for (int off = 1; off < 32; off <<= 1) part += __shfl_xor(part, off, 64);
            if (tx == 0) atomicAdd(&outp[b], part * mask[(size_t)b*NA + n]);
        }
        return;
    }

    float psum[8], psq[8];
    #pragma unroll
    for (int i = 0; i < 8; i++) { psum[i] = 0.f; psq[i] = 0.f; }

    #pragma unroll
    for (int i = 0; i < 8; i++) {
        int row = mrow0 + ty*8 + i;
        bf16 tmp[NPT] __attribute__((aligned(16)));
        #pragma unroll
        for (int j = 0; j < NPT; j++) {
            float v = acc[i][j] + bsv[j];
            tmp[j] = f2bf(v);
            psum[i] += v; psq[i] += v*v;
        }
        if constexpr (MODE == 0) {
            size_t gro = ((size_t)bbase*NA + row) * DOUT;
            if constexpr (NPT == 8) *(uint4*)(hout + gro + tx*NPT) = *(uint4*)tmp;
            else                    *(uint2*)(hout + gro + tx*NPT) = *(uint2*)tmp;
        }
    }
    #pragma unroll
    for (int i = 0; i < 8; i++) {
        float s = psum[i], q = psq[i];
        #pragma unroll
        for (int off = 1; off < 32; off <<= 1) {
            s += __shfl_xor(s, off, 64);
            q += __shfl_xor(q, off, 64);
        }
        if (tx == 0) { rowsum[ty*8+i][0] = s; rowsum[ty*8+i][1] = q; }
    }
    __syncthreads();
    if (tid < 64) {
        int m = (mrow0 + tid) % 9;     // bbase*9 divisible by 9
        atomicAdd(&bstat[m],   rowsum[tid][0]);
        atomicAdd(&bstat[9+m], rowsum[tid][1]);
    }
    __syncthreads();
    if (tid < 9) {
        float* sl = slots + (size_t)(blockIdx.x & (NSLOT-1)) * 32;
        atomicAdd(&sl[tid],    bstat[tid]);
        atomicAdd(&sl[16+tid], bstat[9+tid]);
    }
}

// ---------------- Path-A readout ----------------
__global__ __launch_bounds__(256) void k_readout(
    const bf16* __restrict__ h2,       // [B,9,256]
    const float* __restrict__ fin,
    const float* __restrict__ mask,    // [B,9]
    const float* __restrict__ fcw,     // [256]
    const float* __restrict__ fcb,
    float* __restrict__ out)           // [B]
{
    int tid = threadIdx.x;
    int w = tid >> 6, lane = tid & 63;
    int b = blockIdx.x * 4 + w;
    float sc[9], sh[9];
    #pragma unroll
    for (int n = 0; n < 9; n++) { sc[n] = fin[n]; sh[n] = fin[16+n]; }
    const bf16* hp = h2 + (size_t)b * (NA*D3) + lane*4;
    float acc0 = 0.f, acc1 = 0.f, acc2 = 0.f, acc3 = 0.f;
    #pragma unroll
    for (int n = 0; n < 9; n++) {
        bf16 v4[4] __attribute__((aligned(8)));
        *(uint2*)v4 = *(const uint2*)(hp + n*D3);
        float mk = mask[(size_t)b*NA + n];
        float v;
        v = sc[n]*bf2f(v4[0]) + sh[n]; v = v > 0.f ? v : SLOPE*v; acc0 += v*mk;
        v = sc[n]*bf2f(v4[1]) + sh[n]; v = v > 0.f ? v : SLOPE*v; acc1 += v*mk;
        v = sc[n]*bf2f(v4[2]) + sh[n]; v = v > 0.f ? v : SLOPE*v; acc2 += v*mk;
        v = sc[n]*bf2f(v4[3]) + sh[n]; v = v > 0.f ? v : SLOPE*v; acc3 += v*mk;
    }
    float4 wv = *(const float4*)(fcw + lane*4);
    float s = acc0*wv.x + acc1*wv.y + acc2*wv.z + acc3*wv.w;
    #pragma unroll
    for (int off = 1; off < 64; off <<= 1) s += __shfl_xor(s, off, 64);
    if (lane == 0) out[b] = s + fcb[0];
}

__global__ __launch_bounds__(256) void k_addfcb(float* __restrict__ out, const float* __restrict__ fcb)
{
    int idx = blockIdx.x * 256 + threadIdx.x;
    if (idx < NB) out[idx] += fcb[0];
}

// ---------------- workspace layouts ----------------
// header [0, 32768): slots 3*64*32 f @0, fins 3*32 f @24576
// Path A (ws >= 250,118,144 B):
//   Z  @ 32768          (23,592,960 B; shared by layer1/layer2 chunk sizes)
//   h1 @ 23,625,728     (75,497,472 B)
//   h2 @ 99,123,200     (150,994,944 B)   [h0 aliased at h2 base: 37,748,736 B, dead
//                                          before first h2 write]
// Path B (needs 136,871,936 B): no h2; layer-2 computed twice (stats pass + fused readout)
//   Z  @ 32768, h0 @ 23,625,728, h1 @ 61,374,464

extern "C" void kernel_launch(void* const* d_in, const int* in_sizes, int n_in,
                              void* d_out, int out_size, void* d_ws, size_t ws_size,
                              hipStream_t stream)
{
    const float* feats = (const float*)d_in[0];
    const float* adj   = (const float*)d_in[1];
    const float* mask  = (const float*)d_in[2];
    const float* ws0 = (const float*)d_in[3];
    const float* wr0 = (const float*)d_in[4];
    const float* b0  = (const float*)d_in[5];
    const float* g0  = (const float*)d_in[6];
    const float* be0 = (const float*)d_in[7];
    const float* ws1 = (const float*)d_in[8];
    const float* wr1 = (const float*)d_in[9];
    const float* b1  = (const float*)d_in[10];
    const float* g1  = (const float*)d_in[11];
    const float* be1 = (const float*)d_in[12];
    const float* ws2 = (const float*)d_in[13];
    const float* wr2 = (const float*)d_in[14];
    const float* b2  = (const float*)d_in[15];
    const float* g2  = (const float*)d_in[16];
    const float* be2 = (const float*)d_in[17];
    const float* fcw = (const float*)d_in[18];
    const float* fcb = (const float*)d_in[19];
    float* outp = (float*)d_out;

    char* wsb = (char*)d_ws;
    float* slots0 = (float*)(wsb + 0);
    float* slots1 = slots0 + NSLOT*32;
    float* slots2 = slots1 + NSLOT*32;
    float* fin0 = (float*)(wsb + 24576);
    float* fin1 = fin0 + 32;
    float* fin2 = fin1 + 32;
    bf16* Z = (bf16*)(wsb + 32768ULL);

    bool bigws = (ws_size >= 250118144ULL);

    k_zero<<<(NB+255)/256, 256, 0, stream>>>((float*)wsb, outp);

    if (bigws) {
        bf16* h1 = (bf16*)(wsb + 23625728ULL);
        bf16* h2 = (bf16*)(wsb + 99123200ULL);
        bf16* h0 = h2;   // alias: h0 dead before first h2 write

        k_layer0<<<NB/4, 256, 0, stream>>>(feats, adj, ws0, wr0, b0, h0, slots0);
        k_finalize<D1><<<1, 64, 0, stream>>>(slots0, g0, be0, fin0);

        for (int c = 0; c < NB/CHB1; c++) {
            int bbase = c * CHB1;
            k_pre<D1><<<CHB1/4, 256, 0, stream>>>(h0, fin0, adj, Z, bbase);
            k_gemm<D1, D2, 0><<<(CHB1*NA)/64, 256, 0, stream>>>(
                Z, ws1, wr1, b1, h1, slots1, bbase, nullptr, nullptr, nullptr, nullptr);
        }
        k_finalize<D2><<<1, 64, 0, stream>>>(slots1, g1, be1, fin1);

        for (int c = 0; c < NB/CHB2; c++) {
            int bbase = c * CHB2;
            k_pre<D2><<<CHB2/4, 256, 0, stream>>>(h1, fin1, adj, Z, bbase);
            k_gemm<D2, D3, 0><<<(CHB2*NA)/64, 256, 0, stream>>>(
                Z, ws2, wr2, b2, h2, slots2, bbase, nullptr, nullptr, nullptr, nullptr);
        }
        k_finalize<D3><<<1, 64, 0, stream>>>(slots2, g2, be2, fin2);

        k_readout<<<NB/4, 256, 0, stream>>>(h2, fin2, mask, fcw, fcb, outp);
    } else {
        bf16* h0 = (bf16*)(wsb + 23625728ULL);
        bf16* h1 = (bf16*)(wsb + 61374464ULL);

        k_layer0<<<NB/4, 256, 0, stream>>>(feats, adj, ws0, wr0, b0, h0, slots0);
        k_finalize<D1><<<1, 64, 0, stream>>>(slots0, g0, be0, fin0);

        for (int c = 0; c < NB/CHB1; c++) {
            int bbase = c * CHB1;
            k_pre<D1><<<CHB1/4, 256, 0, stream>>>(h0, fin0, adj, Z, bbase);
            k_gemm<D1, D2, 0><<<(CHB1*NA)/64, 256, 0, stream>>>(
                Z, ws1, wr1, b1, h1, slots1, bbase, nullptr, nullptr, nullptr, nullptr);
        }
        k_finalize<D2><<<1, 64, 0, stream>>>(slots1, g1, be1, fin1);

        // layer-2 pass 1: stats only
        for (int c = 0; c < NB/CHB2; c++) {
            int bbase = c * CHB2;
            k_pre<D2><<<CHB2/4, 256, 0, stream>>>(h1, fin1, adj, Z, bbase);
            k_gemm<D2, D3, 1><<<(CHB2*NA)/64, 256, 0, stream>>>(
                Z, ws2, wr2, b2, nullptr, slots2, bbase, nullptr, nullptr, nullptr, nullptr);
        }
        k_finalize<D3><<<1, 64, 0, stream>>>(slots2, g2, be2, fin2);

        // layer-2 pass 2: recompute + fused BN/leaky/mask/fc readout
        for (int c = 0; c < NB/CHB2; c++) {
            int bbase = c * CHB2;
            k_pre<D2><<<CHB2/4, 256, 0, stream>>>(h1, fin1, adj, Z, bbase);
            k_gemm<D2, D3, 2><<<(CHB2*NA)/64, 256, 0, stream>>>(
                Z, ws2, wr2, b2, nullptr, nullptr, bbase, fin2, mask, fcw, outp);
        }
        k_addfcb<<<(NB+255)/256, 256, 0, stream>>>(outp, fcb);
    }
}

// Round 3
// 627.408 us; speedup vs baseline: 5.2428x; 5.2428x over previous
//
#include <hip/hip_runtime.h>
#include <hip/hip_bf16.h>

// MolGAN discriminator: 3x RGCN(+BN over atom axis+LeakyReLU) + masked-sum readout.
// R3: bf16 MFMA GEMM with fused Z-construction.
//   Per layer: hpre = [act(h) | adj_r@act(h)]_cat @ Wcat + bias, one kernel, 4608 blocks.
//   Block = 64 rows (<=9 molecules) x full DOUT. act(h) + adj staged in LDS; Y_r chunks
//   built on the fly into double-buffered LDS; A-frags from LDS, B-frags from L2-resident
//   pre-transposed bf16 Wcat^T. BN stats accumulated in epilogue (exact fp32).
// Path A (ws >= 227 MB): store h2, separate readout. Path B: layer-2 twice (stats pass +
// fused BN/leaky/mask/fc readout epilogue).

#define NB 32768
#define NA 9
#define NR 4
#define D0 5
#define D1 64
#define D2 128
#define D3 256
#define EPS 1e-5f
#define SLOPE 0.2f
#define NSLOT 64

typedef __hip_bfloat16 bf16;
typedef short bf16x8 __attribute__((ext_vector_type(8)));
typedef float f32x4 __attribute__((ext_vector_type(4)));

__device__ __forceinline__ float bf2f(bf16 v) { return __bfloat162float(v); }
__device__ __forceinline__ bf16  f2bf(float v) { return __float2bfloat16(v); }

// ---------------- zero init: stats slots + fins + out ----------------
__global__ __launch_bounds__(256) void k_zero(float* __restrict__ hdr, float* __restrict__ out)
{
    int idx = blockIdx.x * 256 + threadIdx.x;
    if (idx < NB) out[idx] = 0.f;
    if (idx < 6240) hdr[idx] = 0.f;   // 3*64*32 slots + 3*32 fins
}

// ---------------- weight prep: Wcat^T [DOUT][5*DIN] bf16 ----------------
template<int DIN, int DOUT>
__global__ __launch_bounds__(256) void k_prep(const float* __restrict__ ws,
                                              const float* __restrict__ wr,
                                              bf16* __restrict__ wt)
{
    constexpr int K5 = 5*DIN;
    int idx = blockIdx.x*256 + threadIdx.x;
    if (idx >= DOUT*K5) return;
    int n = idx / K5, k = idx % K5;
    int s = k / DIN, kk = k % DIN;
    float v = (s == 0) ? ws[(size_t)kk*DOUT + n]
                       : wr[((size_t)(s-1)*DIN + kk)*DOUT + n];
    wt[idx] = f2bf(v);
}

// ---------------- layer 0 (din=5) ----------------
__global__ __launch_bounds__(256) void k_layer0(
    const float* __restrict__ feats,   // [B,9,5]
    const float* __restrict__ adj,     // [B,4,9,9]
    const float* __restrict__ ws,      // [5,64]
    const float* __restrict__ wr,      // [4,5,64]
    const float* __restrict__ bias,    // [64]
    bf16* __restrict__ hpre,           // [B,9,64]
    float* __restrict__ slots)
{
    __shared__ float Wsh[5][5][64];
    __shared__ float Bsh[64];
    __shared__ float Adj[4][4][9][9];
    __shared__ float Hsh[4][9][5];
    __shared__ float bstat[18];

    int tid = threadIdx.x;
    int bl  = tid >> 6;
    int e   = tid & 63;
    int b0  = blockIdx.x * 4;

    for (int i = tid; i < 5*64; i += 256) Wsh[0][i/64][i%64] = ws[i];
    for (int i = tid; i < 4*5*64; i += 256) {
        int s = i / 320, rem = i % 320;
        Wsh[1+s][rem/64][rem%64] = wr[i];
    }
    if (tid < 64) Bsh[tid] = bias[tid];
    if (tid < 18) bstat[tid] = 0.f;
    {
        const float* ap = adj + (size_t)(b0 + bl) * (NR*NA*NA);
        float* dst = &Adj[bl][0][0][0];
        for (int i = e; i < NR*NA*NA; i += 64) dst[i] = ap[i];
    }
    {
        const float* fp = feats + (size_t)(b0 + bl) * (NA*D0);
        float* dst = &Hsh[bl][0][0];
        for (int i = e; i < NA*D0; i += 64) dst[i] = fp[i];
    }
    __syncthreads();

    float X[5][9];
    #pragma unroll
    for (int s = 0; s < 5; s++)
        #pragma unroll
        for (int n = 0; n < 9; n++) {
            float a = 0.f;
            #pragma unroll
            for (int k = 0; k < 5; k++) a += Hsh[bl][n][k] * Wsh[s][k][e];
            X[s][n] = a;
        }
    float bv = Bsh[e];
    float out[9];
    #pragma unroll
    for (int m = 0; m < 9; m++) {
        float a = X[0][m] + bv;
        #pragma unroll
        for (int r = 0; r < 4; r++)
            #pragma unroll
            for (int n = 0; n < 9; n++)
                a += Adj[bl][r][m][n] * X[1+r][n];
        out[m] = a;
    }
    bf16* hp = hpre + (size_t)(b0 + bl) * (NA*D1) + e;
    #pragma unroll
    for (int m = 0; m < 9; m++) hp[m*D1] = f2bf(out[m]);

    #pragma unroll
    for (int m = 0; m < 9; m++) {
        float s = out[m], q = out[m]*out[m];
        #pragma unroll
        for (int off = 32; off > 0; off >>= 1) {
            s += __shfl_xor(s, off, 64);
            q += __shfl_xor(q, off, 64);
        }
        if (e == 0) { atomicAdd(&bstat[m], s); atomicAdd(&bstat[9+m], q); }
    }
    __syncthreads();
    if (tid < 9) {
        float* sl = slots + (size_t)(blockIdx.x & (NSLOT-1)) * 32;
        atomicAdd(&sl[tid],      bstat[tid]);
        atomicAdd(&sl[16+tid],   bstat[9+tid]);
    }
}

// ---------------- BN finalize ----------------
template<int DOUT>
__global__ void k_finalize(const float* __restrict__ slots,
                           const float* __restrict__ g, const float* __restrict__ be,
                           float* __restrict__ fin)
{
    int n = threadIdx.x;
    if (n < 9) {
        float s = 0.f, q = 0.f;
        for (int i = 0; i < NSLOT; i++) { s += slots[i*32+n]; q += slots[i*32+16+n]; }
        float cnt = (float)NB * (float)DOUT;
        float mean = s / cnt;
        float var  = q / cnt - mean*mean;
        float sc   = g[n] * rsqrtf(var + EPS);
        fin[n]    = sc;
        fin[16+n] = be[n] - mean * sc;
    }
}

// ---------------- Y chunk build: ydst[64][40] = adj_r @ act(h) cols [k0c,k0c+32) ----------------
template<int DIN>
__device__ __forceinline__ void buildY(int j, int tid, int off,
    const bf16* hS, const float* adjS, bf16* ydst)
{
    constexpr int HS = DIN + 8;
    constexpr int KS = DIN/32;
    int r = j / KS, k0c = (j % KS)*32;
    #pragma unroll
    for (int ii = 0; ii < 2; ii++) {
        int i = tid + ii*256;
        int row_l = i >> 3;
        int c4 = (i & 7)*4;
        int loc = off + row_l;
        int ml = loc / 9;
        int a = loc - ml*9;
        const float* apj = adjS + ml*324 + r*81 + a*9;
        const bf16* hp = hS + (ml*9)*HS + k0c + c4;
        float f0=0.f, f1=0.f, f2=0.f, f3=0.f;
        #pragma unroll
        for (int n = 0; n < 9; n++) {
            float av = apj[n];
            bf16 hv[4] __attribute__((aligned(8)));
            *(uint2*)hv = *(const uint2*)(hp + n*HS);
            f0 += av*bf2f(hv[0]); f1 += av*bf2f(hv[1]);
            f2 += av*bf2f(hv[2]); f3 += av*bf2f(hv[3]);
        }
        bf16 ov[4] __attribute__((aligned(8)));
        ov[0]=f2bf(f0); ov[1]=f2bf(f1); ov[2]=f2bf(f2); ov[3]=f2bf(f3);
        *(uint2*)(ydst + row_l*40 + c4) = *(uint2*)ov;
    }
}

// ---------------- fused RGCN layer: MFMA GEMM over K5=5*DIN ----------------
// MODE 0: store hout + stats.  MODE 1: stats only.  MODE 2: fused readout epilogue.
template<int DIN, int DOUT, int MODE>
__global__ __launch_bounds__(256, 3) void k_mfma(
    const bf16*  __restrict__ hprev,   // [B,9,DIN]
    const float* __restrict__ finPrev, // prev-layer BN affine [32]
    const float* __restrict__ adjg,    // [B,4,9,9]
    const bf16*  __restrict__ wt,      // [DOUT][5*DIN] bf16 (Wcat^T)
    const float* __restrict__ bias,    // [DOUT]
    bf16*  __restrict__ hout,          // [B,9,DOUT] (MODE 0)
    float* __restrict__ slots,         // (MODE 0/1)
    const float* __restrict__ finC,    // this-layer BN affine (MODE 2)
    const float* __restrict__ maskg,   // [B,9] (MODE 2)
    const float* __restrict__ fcw,     // [DOUT] (MODE 2)
    float* __restrict__ outp)          // [B] (MODE 2)
{
    constexpr int K5 = 5*DIN;
    constexpr int HS = DIN + 8;        // h row stride (elems); 16B-mult, conflict-free b128
    constexpr int NT = DOUT/64;        // N-tiles per wave
    constexpr int KS = DIN/32;         // K-steps per section
    constexpr int NRS = 4*KS;          // relation K-steps

    __shared__ __align__(16) bf16 hS[81*HS];
    __shared__ __align__(16) bf16 yS[2*64*40];
    __shared__ float adjS[9*324];
    __shared__ float rstat[128];
    __shared__ float sfinP[32];
    __shared__ float sfinC[32];

    int tid = threadIdx.x;
    int row0 = blockIdx.x * 64;
    int mol_lo = row0 / 9;
    int mol_hi = (row0 + 63) / 9;
    int nmol = mol_hi - mol_lo + 1;
    int off = row0 - mol_lo*9;         // h-local index of global row0

    if (tid < 32) sfinP[tid] = finPrev[tid];
    if constexpr (MODE == 2) { if (tid >= 32 && tid < 64) sfinC[tid-32] = finC[tid-32]; }
    if (tid >= 64 && tid < 192) rstat[tid-64] = 0.f;
    for (int i = tid; i < nmol*324; i += 256) adjS[i] = adjg[(size_t)mol_lo*324 + i];
    __syncthreads();

    // stage act(h_prev): affine (prev BN) + leaky, bf16, padded rows
    constexpr int HW4 = DIN/4;
    for (int i = tid; i < nmol*9*HW4; i += 256) {
        int rl = i / HW4;
        int a  = rl % 9;
        int c4 = (i % HW4)*4;
        bf16 hv[4] __attribute__((aligned(8)));
        *(uint2*)hv = *(const uint2*)(hprev + (size_t)(mol_lo*9 + rl)*DIN + c4);
        float sc = sfinP[a], sh = sfinP[16+a];
        bf16 ov[4] __attribute__((aligned(8)));
        #pragma unroll
        for (int jj = 0; jj < 4; jj++) {
            float v = sc*bf2f(hv[jj]) + sh;
            v = v > 0.f ? v : SLOPE*v;
            ov[jj] = f2bf(v);
        }
        *(uint2*)(&hS[rl*HS + c4]) = *(uint2*)ov;
    }
    __syncthreads();

    int wv = tid >> 6, lane = tid & 63;
    int q = lane >> 4, l15 = lane & 15;

    f32x4 acc[4][NT];
    #pragma unroll
    for (int mt = 0; mt < 4; mt++)
        #pragma unroll
        for (int t = 0; t < NT; t++) acc[mt][t] = (f32x4){0.f, 0.f, 0.f, 0.f};

    const bf16* wp[NT];
    #pragma unroll
    for (int t = 0; t < NT; t++) {
        int ncol = (wv*NT + t)*16 + l15;
        wp[t] = wt + (size_t)ncol*K5 + q*8;
    }

    // --- section 0: A-frags directly from hS ---
    #pragma unroll
    for (int ks = 0; ks < KS; ks++) {
        bf16x8 Af[4], Bf[NT];
        #pragma unroll
        for (int mt = 0; mt < 4; mt++)
            Af[mt] = *(const bf16x8*)(hS + (size_t)(off + mt*16 + l15)*HS + ks*32 + q*8);
        #pragma unroll
        for (int t = 0; t < NT; t++)
            Bf[t] = *(const bf16x8*)(wp[t] + ks*32);
        #pragma unroll
        for (int mt = 0; mt < 4; mt++)
            #pragma unroll
            for (int t = 0; t < NT; t++)
                acc[mt][t] = __builtin_amdgcn_mfma_f32_16x16x32_bf16(Af[mt], Bf[t], acc[mt][t], 0, 0, 0);
    }

    // --- relation sections: double-buffered Y chunks ---
    buildY<DIN>(0, tid, off, hS, adjS, yS);
    __syncthreads();
    for (int j = 0; j < NRS; j++) {
        int kc = KS + j;
        const bf16* yb = yS + (size_t)(j & 1)*(64*40);
        bf16x8 Af[4], Bf[NT];
        #pragma unroll
        for (int mt = 0; mt < 4; mt++)
            Af[mt] = *(const bf16x8*)(yb + (size_t)(mt*16 + l15)*40 + q*8);
        #pragma unroll
        for (int t = 0; t < NT; t++)
            Bf[t] = *(const bf16x8*)(wp[t] + kc*32);
        #pragma unroll
        for (int mt = 0; mt < 4; mt++)
            #pragma unroll
            for (int t = 0; t < NT; t++)
                acc[mt][t] = __builtin_amdgcn_mfma_f32_16x16x32_bf16(Af[mt], Bf[t], acc[mt][t], 0, 0, 0);
        if (j + 1 < NRS)
            buildY<DIN>(j + 1, tid, off, hS, adjS, yS + (size_t)((j + 1) & 1)*(64*40));
        __syncthreads();
    }

    // --- epilogue ---
    float bcol[NT];
    #pragma unroll
    for (int t = 0; t < NT; t++) bcol[t] = bias[(wv*NT + t)*16 + l15];

    if constexpr (MODE == 2) {
        float fwv[NT];
        #pragma unroll
        for (int t = 0; t < NT; t++) fwv[t] = fcw[(wv*NT + t)*16 + l15];
        #pragma unroll
        for (int mt = 0; mt < 4; mt++) {
            #pragma unroll
            for (int reg = 0; reg < 4; reg++) {
                int rloc = mt*16 + q*4 + reg;
                int atom = (row0 + rloc) % 9;
                float sc = sfinC[atom], sh = sfinC[16+atom];
                float part = 0.f;
                #pragma unroll
                for (int t = 0; t < NT; t++) {
                    float v = acc[mt][t][reg] + bcol[t];
                    float y = sc*v + sh;
                    y = y > 0.f ? y : SLOPE*y;
                    part += y * fwv[t];
                }
                part += __shfl_xor(part, 1); part += __shfl_xor(part, 2);
                part += __shfl_xor(part, 4); part += __shfl_xor(part, 8);
                if (l15 == 0) atomicAdd(&rstat[rloc], part);
            }
        }
        __syncthreads();
        if (tid < 64) {
            int rg = row0 + tid;
            int b = rg / 9;
            atomicAdd(&outp[b], rstat[tid] * maskg[rg]);
        }
        return;
    }

    #pragma unroll
    for (int mt = 0; mt < 4; mt++) {
        #pragma unroll
        for (int reg = 0; reg < 4; reg++) {
            int rloc = mt*16 + q*4 + reg;
            float s = 0.f, qq = 0.f;
            #pragma unroll
            for (int t = 0; t < NT; t++) {
                float v = acc[mt][t][reg] + bcol[t];
                if constexpr (MODE == 0) {
                    size_t o = (size_t)(row0 + rloc)*DOUT + (wv*NT + t)*16 + l15;
                    hout[o] = f2bf(v);
                }
                s += v; qq += v*v;
            }
            s += __shfl_xor(s, 1); s += __shfl_xor(s, 2);
            s += __shfl_xor(s, 4); s += __shfl_xor(s, 8);
            qq += __shfl_xor(qq, 1); qq += __shfl_xor(qq, 2);
            qq += __shfl_xor(qq, 4); qq += __shfl_xor(qq, 8);
            if (l15 == 0) { atomicAdd(&rstat[rloc*2], s); atomicAdd(&rstat[rloc*2+1], qq); }
        }
    }
    __syncthreads();
    if (tid < 64) {
        int rg = row0 + tid;
        int atom = rg % 9;
        float* sl = slots + (size_t)(blockIdx.x & (NSLOT-1))*32;
        atomicAdd(&sl[atom],    rstat[tid*2]);
        atomicAdd(&sl[16+atom], rstat[tid*2+1]);
    }
}

// ---------------- Path-A readout ----------------
__global__ __launch_bounds__(256) void k_readout(
    const bf16* __restrict__ h2,
    const float* __restrict__ fin,
    const float* __restrict__ mask,
    const float* __restrict__ fcw,
    const float* __restrict__ fcb,
    float* __restrict__ out)
{
    int tid = threadIdx.x;
    int w = tid >> 6, lane = tid & 63;
    int b = blockIdx.x * 4 + w;
    float sc[9], sh[9];
    #pragma unroll
    for (int n = 0; n < 9; n++) { sc[n] = fin[n]; sh[n] = fin[16+n]; }
    const bf16* hp = h2 + (size_t)b * (NA*D3) + lane*4;
    float acc0 = 0.f, acc1 = 0.f, acc2 = 0.f, acc3 = 0.f;
    #pragma unroll
    for (int n = 0; n < 9; n++) {
        bf16 v4[4] __attribute__((aligned(8)));
        *(uint2*)v4 = *(const uint2*)(hp + n*D3);
        float mk = mask[(size_t)b*NA + n];
        float v;
        v = sc[n]*bf2f(v4[0]) + sh[n]; v = v > 0.f ? v : SLOPE*v; acc0 += v*mk;
        v = sc[n]*bf2f(v4[1]) + sh[n]; v = v > 0.f ? v : SLOPE*v; acc1 += v*mk;
        v = sc[n]*bf2f(v4[2]) + sh[n]; v = v > 0.f ? v : SLOPE*v; acc2 += v*mk;
        v = sc[n]*bf2f(v4[3]) + sh[n]; v = v > 0.f ? v : SLOPE*v; acc3 += v*mk;
    }
    float4 wv = *(const float4*)(fcw + lane*4);
    float s = acc0*wv.x + acc1*wv.y + acc2*wv.z + acc3*wv.w;
    #pragma unroll
    for (int off = 1; off < 64; off <<= 1) s += __shfl_xor(s, off, 64);
    if (lane == 0) out[b] = s + fcb[0];
}

__global__ __launch_bounds__(256) void k_addfcb(float* __restrict__ out, const float* __restrict__ fcb)
{
    int idx = blockIdx.x * 256 + threadIdx.x;
    if (idx < NB) out[idx] += fcb[0];
}

// ---------------- workspace layout ----------------
// [0, 24960)      : slots 3*64*32 f + fins 3*32 f
// [32768, 114688) : wt1 bf16 [128][320]
// [114688, 442368): wt2 bf16 [256][640]
// [524288, ...)   : Path A: h1 (75,497,472) @524288; h2 (150,994,944) @76,021,760;
//                   h0 aliased at h2 base (dead before h2 written). End = 227,016,704.
//                   Path B: h0 @524288 (37,748,736); h1 @38,273,024. End = 113,770,496.

extern "C" void kernel_launch(void* const* d_in, const int* in_sizes, int n_in,
                              void* d_out, int out_size, void* d_ws, size_t ws_size,
                              hipStream_t stream)
{
    const float* feats = (const float*)d_in[0];
    const float* adj   = (const float*)d_in[1];
    const float* mask  = (const float*)d_in[2];
    const float* ws0 = (const float*)d_in[3];
    const float* wr0 = (const float*)d_in[4];
    const float* b0  = (const float*)d_in[5];
    const float* g0  = (const float*)d_in[6];
    const float* be0 = (const float*)d_in[7];
    const float* ws1 = (const float*)d_in[8];
    const float* wr1 = (const float*)d_in[9];
    const float* b1  = (const float*)d_in[10];
    const float* g1  = (const float*)d_in[11];
    const float* be1 = (const float*)d_in[12];
    const float* ws2 = (const float*)d_in[13];
    const float* wr2 = (const float*)d_in[14];
    const float* b2  = (const float*)d_in[15];
    const float* g2  = (const float*)d_in[16];
    const float* be2 = (const float*)d_in[17];
    const float* fcw = (const float*)d_in[18];
    const float* fcb = (const float*)d_in[19];
    float* outp = (float*)d_out;

    char* wsb = (char*)d_ws;
    float* slots0 = (float*)(wsb + 0);
    float* slots1 = slots0 + NSLOT*32;
    float* slots2 = slots1 + NSLOT*32;
    float* fin0 = (float*)(wsb + 24576);
    float* fin1 = fin0 + 32;
    float* fin2 = fin1 + 32;
    bf16* wt1 = (bf16*)(wsb + 32768);
    bf16* wt2 = (bf16*)(wsb + 114688);

    k_zero<<<(NB+255)/256, 256, 0, stream>>>((float*)wsb, outp);
    k_prep<D1, D2><<<(D2*5*D1 + 255)/256, 256, 0, stream>>>(ws1, wr1, wt1);
    k_prep<D2, D3><<<(D3*5*D2 + 255)/256, 256, 0, stream>>>(ws2, wr2, wt2);

    bool bigws = (ws_size >= 227016704ULL);
    const int GRID = (NB*NA)/64;   // 4608

    if (bigws) {
        bf16* h1 = (bf16*)(wsb + 524288ULL);
        bf16* h2 = (bf16*)(wsb + 76021760ULL);
        bf16* h0 = h2;   // alias: h0 fully consumed before first h2 write

        k_layer0<<<NB/4, 256, 0, stream>>>(feats, adj, ws0, wr0, b0, h0, slots0);
        k_finalize<D1><<<1, 64, 0, stream>>>(slots0, g0, be0, fin0);

        k_mfma<D1, D2, 0><<<GRID, 256, 0, stream>>>(
            h0, fin0, adj, wt1, b1, h1, slots1, nullptr, nullptr, nullptr, nullptr);
        k_finalize<D2><<<1, 64, 0, stream>>>(slots1, g1, be1, fin1);

        k_mfma<D2, D3, 0><<<GRID, 256, 0, stream>>>(
            h1, fin1, adj, wt2, b2, h2, slots2, nullptr, nullptr, nullptr, nullptr);
        k_finalize<D3><<<1, 64, 0, stream>>>(slots2, g2, be2, fin2);

        k_readout<<<NB/4, 256, 0, stream>>>(h2, fin2, mask, fcw, fcb, outp);
    } else {
        bf16* h0 = (bf16*)(wsb + 524288ULL);
        bf16* h1 = (bf16*)(wsb + 38273024ULL);

        k_layer0<<<NB/4, 256, 0, stream>>>(feats, adj, ws0, wr0, b0, h0, slots0);
        k_finalize<D1><<<1, 64, 0, stream>>>(slots0, g0, be0, fin0);

        k_mfma<D1, D2, 0><<<GRID, 256, 0, stream>>>(
            h0, fin0, adj, wt1, b1, h1, slots1, nullptr, nullptr, nullptr, nullptr);
        k_finalize<D2><<<1, 64, 0, stream>>>(slots1, g1, be1, fin1);

        k_mfma<D2, D3, 1><<<GRID, 256, 0, stream>>>(
            h1, fin1, adj, wt2, b2, nullptr, slots2, nullptr, nullptr, nullptr, nullptr);
        k_finalize<D3><<<1, 64, 0, stream>>>(slots2, g2, be2, fin2);

        k_mfma<D2, D3, 2><<<GRID, 256, 0, stream>>>(
            h1, fin1, adj, wt2, b2, nullptr, nullptr, fin2, mask, fcw, outp);
        k_addfcb<<<(NB+255)/256, 256, 0, stream>>>(outp, fcb);
    }
}